// Round 21
// baseline (90.139 us; speedup 1.0000x reference)
//
#include <hip/hip_runtime.h>
#include <hip/hip_bf16.h>
#include <stdint.h>
#include <math.h>

// DynaLoRALinear bf16-MFMA, 3-kernel pipeline (r21: x-convert un-fused back to prep).
// prep(x->xb + weights) -> gemm_h(xb via gload_lds; h-GEMM + router softmax +
// fused w=(x@A2^T)*gate) -> gemm_out(256^2, 8-phase).
// out = [x|w] @ [Wb^T;B2], K=1088.  GEMMs take K runtime (anti-unroll, r12).

#define M_TOK 16384

typedef unsigned short u16;
typedef short bf16x8 __attribute__((ext_vector_type(8)));
typedef float f32x4 __attribute__((ext_vector_type(4)));
typedef __attribute__((address_space(3))) uint32_t lds_u32_t;
typedef __attribute__((address_space(1))) const uint32_t glb_u32_t;

__device__ __forceinline__ u16 f2bf(float f) {
  uint32_t u = __builtin_bit_cast(uint32_t, f);
  return (u16)((u + 0x7fffu + ((u >> 16) & 1u)) >> 16);  // RNE
}

#define VMCNT(n) asm volatile("s_waitcnt vmcnt(%0)" ::"i"(n) : "memory")
#define LGKM0 asm volatile("s_waitcnt lgkmcnt(0)" ::: "memory")
#define BAR asm volatile("s_barrier" ::: "memory")
#define SP(x) __builtin_amdgcn_s_setprio(x)

// ------------- prep: x->bf16 + all weight conversions/gathers (r13-proven) -------------
__global__ __launch_bounds__(256) void prep_k(const float* __restrict__ x,
                                              const float* __restrict__ Wb,
                                              const float* __restrict__ rW1,
                                              const float* __restrict__ rW2,
                                              const float* __restrict__ loraA,
                                              const float* __restrict__ loraB,
                                              u16* __restrict__ xb,
                                              u16* __restrict__ Btb,
                                              u16* __restrict__ W1b,
                                              u16* __restrict__ W2b,
                                              u16* __restrict__ A2b) {
  const int g = blockIdx.x;
  const int tid = threadIdx.x;
  if (g < 16384) {
    int i = g * 256 + tid;
    float4 v = ((const float4*)x)[i];
    ushort4 o;
    o.x = f2bf(v.x); o.y = f2bf(v.y); o.z = f2bf(v.z); o.w = f2bf(v.w);
    ((ushort4*)xb)[i] = o;
  } else if (g < 17408) {
    int i = (g - 16384) * 256 + tid;
    int idx = i * 4;
    int row = idx >> 10, col = idx & 1023;
    float4 v = ((const float4*)Wb)[i];
    ushort4 o;
    o.x = f2bf(v.x); o.y = f2bf(v.y); o.z = f2bf(v.z); o.w = f2bf(v.w);
    *(ushort4*)(Btb + (size_t)row * 1088 + col) = o;
  } else if (g < 17920) {
    int i = (g - 17408) * 256 + tid;
    float4 v = ((const float4*)rW1)[i];
    ushort4 o;
    o.x = f2bf(v.x); o.y = f2bf(v.y); o.z = f2bf(v.z); o.w = f2bf(v.w);
    ((ushort4*)W1b)[i] = o;
  } else if (g < 18176) {
    int idx = (g - 17920) * 256 + tid;
    int n = idx >> 6, q = idx & 63;
    int e = q >> 3, r = q & 7;
    Btb[(size_t)n * 1088 + 1024 + q] = f2bf(loraB[((size_t)(e * 1024 + n)) * 8 + r]);
  } else if (g < 18240) {
    int i = (g - 18176) * 256 + tid;
    float4 v = ((const float4*)loraA)[i];
    ushort4 o;
    o.x = f2bf(v.x); o.y = f2bf(v.y); o.z = f2bf(v.z); o.w = f2bf(v.w);
    ((ushort4*)A2b)[i] = o;
  } else {
    // W2b [16][512] bf16, rows 8..15 zero (MFMA B-operand pad)
    int i = (g - 18240) * 256 + tid;
    int idx = i * 4;
    int row = idx >> 9, col = idx & 511;
    ushort4 o = {0, 0, 0, 0};
    if (row < 8) {
      float4 v = *(const float4*)(rW2 + (size_t)row * 512 + col);
      o.x = f2bf(v.x); o.y = f2bf(v.y); o.z = f2bf(v.z); o.w = f2bf(v.w);
    }
    ((ushort4*)W2b)[i] = o;
  }
}

// ===== gemm_h: BM=64 x BN=512 (full N), xb input, fused router + w-GEMM =====
// A (xb tile, 8 KB) now staged via global_load_lds like B — no reg-staging/cvt/
// xb-store in the K-loop (r14-r20's fused convert cost ~24 us vs ~14.5 saved).
// Per tile: [stage A:1+B:8+A2:1 -> q][VMCNT(10) completes tile t][BAR]
//           [frag reads][40 MFMA][LGKM0 BAR].  Queue uniform 10/wave/tile.
// Epilogue: relu-h -> router MFMA logits -> softmax -> g_lds; wb = wacc*gate.
__global__ __launch_bounds__(512, 2) void gemm_h(const u16* __restrict__ xb,
                                                 const u16* __restrict__ W1b,
                                                 const u16* __restrict__ W2bv,
                                                 const u16* __restrict__ A2bv,
                                                 u16* __restrict__ wb,
                                                 const float* __restrict__ b1,
                                                 const float* __restrict__ b2,
                                                 const float* __restrict__ temp,
                                                 const int K) {
  constexpr int ABUF = 64 * 128;            // 8 KB (x tile)
  constexpr int BBUF = 512 * 128;           // 64 KB (W1 tile)
  constexpr int A2BUF = 64 * 128;           // 8 KB (A2 tile)
  constexpr int BUFB = ABUF + BBUF + A2BUF; // 80 KB
  __shared__ __align__(16) uint8_t lds[2 * BUFB];  // 160 KB

  const int tid = threadIdx.x;
  const int lane = tid & 63, w = tid >> 6;
  const int l15 = lane & 15, lhi = lane >> 4;
  const int xorv = (lane & 7) << 4;
  const int c0 = (lhi * 16) ^ xorv;
  const int c1 = (64 + lhi * 16) ^ xorv;

  const int f = blockIdx.x;
  const int m0 = ((f & 7) * 32 + (f >> 3)) * 64;

  const int nk = K >> 6;
  const int rot = (f >> 3) & (nk - 1);
  auto PH = [&](int l) { int lc = l < nk ? l : nk - 1; return (lc + rot) & (nk - 1); };

  f32x4 acc[4][4] = {};
  f32x4 wacc[4] = {};
  bf16x8 af[4][2], bfv[4][2], a2f[2];

  auto stageA = [&](int ktp, int b) {
    uint8_t* dst = lds + b * BUFB + w * 1024;
    const int off = tid * 16;
    const int row = off >> 7;                   // 0..63
    const int ss = ((off >> 4) & 7) ^ (row & 7);
    const uint8_t* g =
        (const uint8_t*)xb + (size_t)(m0 + row) * 2048 + ktp * 128 + ss * 16;
    __builtin_amdgcn_global_load_lds((glb_u32_t*)g, (lds_u32_t*)dst, 16, 0, 0);
  };
  auto stageBH = [&](int ktp, int b) {
    uint8_t* dst = lds + b * BUFB + ABUF + w * 1024;
#pragma unroll
    for (int i = 0; i < 8; ++i) {
      const int off = i * 8192 + tid * 16;
      const int row = off >> 7;
      const int ss = ((off >> 4) & 7) ^ (row & 7);
      const uint8_t* g =
          (const uint8_t*)W1b + (size_t)row * 2048 + ktp * 128 + ss * 16;
      __builtin_amdgcn_global_load_lds((glb_u32_t*)g, (lds_u32_t*)(dst + i * 8192),
                                       16, 0, 0);
    }
  };
  auto stageA2 = [&](int ktp, int b) {
    uint8_t* dst = lds + b * BUFB + ABUF + BBUF + w * 1024;
    const int off = tid * 16;
    const int row = off >> 7;
    const int ss = ((off >> 4) & 7) ^ (row & 7);
    const uint8_t* g =
        (const uint8_t*)A2bv + (size_t)row * 2048 + ktp * 128 + ss * 16;
    __builtin_amdgcn_global_load_lds((glb_u32_t*)g, (lds_u32_t*)dst, 16, 0, 0);
  };
  auto loadAH = [&](const uint8_t* bufA) {
#pragma unroll
    for (int mf = 0; mf < 4; ++mf) {
      const uint8_t* pr = bufA + (mf * 16 + l15) * 128;
      af[mf][0] = *(const bf16x8*)(pr + c0);
      af[mf][1] = *(const bf16x8*)(pr + c1);
    }
  };
  auto loadBH = [&](const uint8_t* bufB) {
#pragma unroll
    for (int nf = 0; nf < 4; ++nf) {
      const uint8_t* pr = bufB + (w * 64 + nf * 16 + l15) * 128;
      bfv[nf][0] = *(const bf16x8*)(pr + c0);
      bfv[nf][1] = *(const bf16x8*)(pr + c1);
    }
  };
  auto loadA2 = [&](const uint8_t* base) {
    const uint8_t* pr = base + ABUF + BBUF + ((w & 3) * 16 + l15) * 128;
    a2f[0] = *(const bf16x8*)(pr + c0);
    a2f[1] = *(const bf16x8*)(pr + c1);
  };

#define HMM()                                                                  \
  _Pragma("unroll") for (int mf = 0; mf < 4; ++mf)                             \
  _Pragma("unroll") for (int nf = 0; nf < 4; ++nf)                             \
  _Pragma("unroll") for (int ks = 0; ks < 2; ++ks)                             \
      acc[mf][nf] = __builtin_amdgcn_mfma_f32_16x16x32_bf16(                   \
          af[mf][ks], bfv[nf][ks], acc[mf][nf], 0, 0, 0);
#define WMM()                                                                  \
  _Pragma("unroll") for (int mf = 0; mf < 4; ++mf)                             \
  _Pragma("unroll") for (int ks = 0; ks < 2; ++ks)                             \
      wacc[mf] = __builtin_amdgcn_mfma_f32_16x16x32_bf16(                      \
          af[mf][ks], a2f[ks], wacc[mf], 0, 0, 0);

  // ---- prologue: tile0 (A+B+A2) -> buf0 ----
  stageA(rot, 0);
  stageBH(rot, 0);
  stageA2(rot, 0);

#pragma unroll 1
  for (int t = 0; t < nk; ++t) {
    const int p = t & 1, q = p ^ 1;
    const uint8_t* bp = (const uint8_t*)lds + p * BUFB;
    // stage tile t+1 into freed buffer q (its reads completed before last BAR)
    stageA(PH(t + 1), q);
    stageBH(PH(t + 1), q);
    stageA2(PH(t + 1), q);
    VMCNT(10);  // completes tile t's 10 loads; leaves t+1's 10 in flight
    BAR;
    loadAH(bp);
    loadBH(bp + ABUF);
    loadA2(bp);
    SP(1); HMM(); WMM(); SP(0);
    LGKM0;      // frag reads drained before next-iter stage overwrites
    BAR;
  }

  // ---- epilogue ----
  u16* hs = (u16*)lds;                       // [64][520] bf16 = 66560 B
  float* g_lds = (float*)(lds + 66560);      // [64][8] f32 = 2 KB
  __syncthreads();  // drains in-flight clamped prefetches + barrier
#pragma unroll
  for (int mf = 0; mf < 4; ++mf) {
#pragma unroll
    for (int nf = 0; nf < 4; ++nf) {
      const int col = w * 64 + nf * 16 + l15;
#pragma unroll
      for (int j = 0; j < 4; ++j) {
        const int row = mf * 16 + lhi * 4 + j;
        float v = fmaxf(acc[mf][nf][j] + b1[col], 0.f);
        hs[row * 520 + col] = f2bf(v);
      }
    }
  }
  __syncthreads();
  if (w < 4) {  // router: wave w -> logits rows w*16..+15, K=512
    f32x4 acc2 = {};
#pragma unroll
    for (int ks = 0; ks < 16; ++ks) {
      bf16x8 bfrag = *(const bf16x8*)(W2bv + (size_t)l15 * 512 + ks * 32 + lhi * 8);
      bf16x8 afrag = *(const bf16x8*)(hs + (w * 16 + l15) * 520 + ks * 32 + lhi * 8);
      acc2 = __builtin_amdgcn_mfma_f32_16x16x32_bf16(afrag, bfrag, acc2, 0, 0, 0);
    }
    if (l15 < 8) {  // lane holds logit[row=w*16+lhi*4+j][e=l15]
      float t = temp[0];
      float lg[4];
#pragma unroll
      for (int j = 0; j < 4; ++j) lg[j] = (acc2[j] + b2[l15]) / t;
      float mx[4], sm[4];
#pragma unroll
      for (int j = 0; j < 4; ++j) mx[j] = lg[j];
#pragma unroll
      for (int m = 1; m <= 4; m <<= 1)
#pragma unroll
        for (int j = 0; j < 4; ++j) mx[j] = fmaxf(mx[j], __shfl_xor(mx[j], m));
#pragma unroll
      for (int j = 0; j < 4; ++j) { lg[j] = expf(lg[j] - mx[j]); sm[j] = lg[j]; }
#pragma unroll
      for (int m = 1; m <= 4; m <<= 1)
#pragma unroll
        for (int j = 0; j < 4; ++j) sm[j] += __shfl_xor(sm[j], m);
#pragma unroll
      for (int j = 0; j < 4; ++j)
        g_lds[(w * 16 + lhi * 4 + j) * 8 + l15] = lg[j] / sm[j];
    }
  }
  __syncthreads();
  if (w < 4) {  // wb = wacc * gate; wave w owns cols w*16..+15, all 64 rows
#pragma unroll
    for (int mf = 0; mf < 4; ++mf) {
#pragma unroll
      for (int j = 0; j < 4; ++j) {
        const int row = mf * 16 + lhi * 4 + j;
        const int col = w * 16 + l15;
        float v = wacc[mf][j] * g_lds[row * 8 + (col >> 3)];
        wb[(size_t)(m0 + row) * 64 + col] = f2bf(v);
      }
    }
  }
}

// ============ gemm_out: r13-proven 8-phase 256^2 (runtime args, rolled loop) ============
#define MFMA_Q2(mh, nh, AF, BF)                                                \
  _Pragma("unroll") for (int im2 = 0; im2 < 4; ++im2)                          \
  _Pragma("unroll") for (int in2 = 0; in2 < 2; ++in2)                          \
  _Pragma("unroll") for (int ks = 0; ks < 2; ++ks)                             \
      acc[(mh) * 4 + im2][(nh) * 2 + in2] =                                    \
          __builtin_amdgcn_mfma_f32_16x16x32_bf16(                             \
              AF[im2][ks], BF[in2][ks],                                        \
              acc[(mh) * 4 + im2][(nh) * 2 + in2], 0, 0, 0);

__global__ __launch_bounds__(512, 2) void gemm_out(const u16* __restrict__ A,
                                                   const u16* __restrict__ Bt,
                                                   const u16* __restrict__ A2,
                                                   float* __restrict__ C,
                                                   const int N, const int K,
                                                   const int lda, const int ldb) {
  constexpr int BM = 256, BN = 256;
  constexpr int VMC = 4;
  constexpr int BUFB = (BM + BN) * 128;

  __shared__ __align__(16) uint8_t lds[2 * BUFB];

  const int tid = threadIdx.x;
  const int lane = tid & 63, w = tid >> 6;
  const int wr = w >> 2, wcn = w & 3;
  const int l15 = lane & 15, lhi = lane >> 4;
  const int xorv = (lane & 7) << 4;
  const int c0 = (lhi * 16) ^ xorv;
  const int c1 = (64 + lhi * 16) ^ xorv;

  const int f = blockIdx.x;
  const int idx = (f & 7) * 32 + (f >> 3);
  const int gx = N / BN;
  const int m0 = (idx / gx) * BM;
  const int n0 = (idx % gx) * BN;

  const size_t lda_b = (size_t)lda * 2, ldb_b = (size_t)ldb * 2;
  const int nk = K >> 6;
  const int arow0 = (wr * (BM / 2) + l15) * 128;
  const int brow0 = (wcn * (BN / 4) + l15) * 128;

  f32x4 acc[8][4] = {};
  bf16x8 A0f[4][2], A1f[4][2];
  bf16x8 B0f[2][2], B1f[2][2];

  auto stageA = [&](int h, int kt, int b) {
    const int ktc = kt < nk ? kt : nk - 1;
    const bool last = (ktc == nk - 1);
    uint8_t* dst = lds + b * BUFB + h * (BM * 64) + w * 1024;
#pragma unroll
    for (int i = 0; i < 2; ++i) {
      const int off = i * 8192 + tid * 16;
      const int row = h * (BM / 2) + (off >> 7);
      const int ss = ((off >> 4) & 7) ^ (row & 7);
      const uint8_t* g =
          last ? (const uint8_t*)A2 + (size_t)(m0 + row) * 128 + ss * 16
               : (const uint8_t*)A + (size_t)(m0 + row) * lda_b + ktc * 128 + ss * 16;
      __builtin_amdgcn_global_load_lds((glb_u32_t*)g, (lds_u32_t*)(dst + i * 8192),
                                       16, 0, 0);
    }
  };
  auto stageB = [&](int h, int kt, int b) {
    const int ktc = kt < nk ? kt : nk - 1;
    uint8_t* dst = lds + b * BUFB + BM * 128 + h * (BN * 64) + w * 1024;
#pragma unroll
    for (int i = 0; i < 2; ++i) {
      const int off = i * 8192 + tid * 16;
      const int row = h * (BN / 2) + (off >> 7);
      const int ss = ((off >> 4) & 7) ^ (row & 7);
      const uint8_t* g =
          (const uint8_t*)Bt + (size_t)(n0 + row) * ldb_b + ktc * 128 + ss * 16;
      __builtin_amdgcn_global_load_lds((glb_u32_t*)g, (lds_u32_t*)(dst + i * 8192),
                                       16, 0, 0);
    }
  };
  auto loadA = [&](int mh, const uint8_t* buf, bf16x8 (&dst)[4][2]) {
#pragma unroll
    for (int im2 = 0; im2 < 4; ++im2) {
      const uint8_t* p = buf + arow0 + mh * (4 * 2048) + im2 * 2048;
      dst[im2][0] = *(const bf16x8*)(p + c0);
      dst[im2][1] = *(const bf16x8*)(p + c1);
    }
  };
  auto loadB = [&](int nh, const uint8_t* buf, bf16x8 (&dst)[2][2]) {
#pragma unroll
    for (int in2 = 0; in2 < 2; ++in2) {
      const uint8_t* p = buf + BM * 128 + brow0 + nh * (2 * 2048) + in2 * 2048;
      dst[in2][0] = *(const bf16x8*)(p + c0);
      dst[in2][1] = *(const bf16x8*)(p + c1);
    }
  };

  const uint8_t* b0 = lds;
  const uint8_t* b1 = lds + BUFB;

  stageA(0, 0, 0); stageA(1, 0, 0);
  stageB(0, 0, 0); stageB(1, 0, 0);
  stageB(0, 1, 1); stageB(1, 1, 1);
  VMCNT(VMC); BAR;
  loadA(0, b0, A0f); loadB(0, b0, B0f);

  const int NIT = nk >> 1;
#pragma unroll 1
  for (int it = 0; it < NIT; ++it) {
    const int t = it * 2;
    // P1
    stageA(0, t + 1, 1);
    BAR;
    SP(1); MFMA_Q2(0, 0, A0f, B0f); SP(0);
    loadB(1, b0, B1f);
    BAR;
    // P2
    stageA(1, t + 1, 1);
    BAR;
    SP(1); MFMA_Q2(0, 1, A0f, B1f); SP(0);
    loadA(1, b0, A1f);
    BAR;
    // P3
    stageB(0, t + 2, 0);
    BAR;
    SP(1); MFMA_Q2(1, 1, A1f, B1f); SP(0);
    BAR;
    // P4
    stageB(1, t + 2, 0);
    VMCNT(VMC);
    BAR;
    SP(1); MFMA_Q2(1, 0, A1f, B0f); SP(0);
    loadA(0, b1, A0f); loadB(0, b1, B0f);
    BAR;
    // P5
    stageA(0, t + 2, 0);
    BAR;
    SP(1); MFMA_Q2(0, 0, A0f, B0f); SP(0);
    loadB(1, b1, B1f);
    BAR;
    // P6
    stageA(1, t + 2, 0);
    BAR;
    SP(1); MFMA_Q2(0, 1, A0f, B1f); SP(0);
    loadA(1, b1, A1f);
    BAR;
    // P7
    stageB(0, t + 3, 1);
    BAR;
    SP(1); MFMA_Q2(1, 1, A1f, B1f); SP(0);
    BAR;
    // P8
    stageB(1, t + 3, 1);
    VMCNT(VMC);
    BAR;
    SP(1); MFMA_Q2(1, 0, A1f, B0f); SP(0);
    loadA(0, b0, A0f); loadB(0, b0, B0f);
    BAR;
  }

  // tail K-tile (odd nk): buf0 holds tile nk-1; A0f/B0f pre-read at last P8
  if (nk & 1) {
    SP(1); MFMA_Q2(0, 0, A0f, B0f); SP(0);
    loadB(1, b0, B1f);
    SP(1); MFMA_Q2(0, 1, A0f, B1f); SP(0);
    loadA(1, b0, A1f);
    SP(1); MFMA_Q2(1, 1, A1f, B1f); MFMA_Q2(1, 0, A1f, B0f); SP(0);
  }

  // epilogue: plain f32 stores, C/D map col=lane&15, row=(lane>>4)*4+j
#pragma unroll
  for (int im = 0; im < 8; ++im) {
#pragma unroll
    for (int in_ = 0; in_ < 4; ++in_) {
      const int col = n0 + wcn * 64 + in_ * 16 + l15;
#pragma unroll
      for (int j = 0; j < 4; ++j) {
        const int row = m0 + wr * 128 + im * 16 + lhi * 4 + j;
        C[(size_t)row * N + col] = acc[im][in_][j];
      }
    }
  }
}

extern "C" void kernel_launch(void* const* d_in, const int* in_sizes, int n_in,
                              void* d_out, int out_size, void* d_ws, size_t ws_size,
                              hipStream_t stream) {
  const float* x     = (const float*)d_in[0];  // [16384][1024]
  const float* Wb    = (const float*)d_in[1];  // [1024][1024]
  const float* rW1   = (const float*)d_in[2];  // [512][1024]
  const float* rb1   = (const float*)d_in[3];  // [512]
  const float* rW2   = (const float*)d_in[4];  // [8][512]
  const float* rb2   = (const float*)d_in[5];  // [8]
  const float* temp  = (const float*)d_in[6];  // [1]
  const float* loraA = (const float*)d_in[7];  // [64][1024]
  const float* loraB = (const float*)d_in[8];  // [8][1024][8]
  float* out = (float*)d_out;

  uint8_t* p = (uint8_t*)d_ws;
  u16* xb    = (u16*)p;   p += (size_t)M_TOK * 1024 * 2;
  u16* wb    = (u16*)p;   p += (size_t)M_TOK * 64 * 2;
  u16* Btb   = (u16*)p;   p += (size_t)1024 * 1088 * 2;
  u16* W1b   = (u16*)p;   p += (size_t)512 * 1024 * 2;
  u16* W2b   = (u16*)p;   p += (size_t)16 * 512 * 2;
  u16* A2b   = (u16*)p;   p += (size_t)64 * 1024 * 2;

  // ---- prep: x->xb + weights ----
  prep_k<<<18248, 256, 0, stream>>>(x, Wb, rW1, rW2, loraA, loraB,
                                    xb, Btb, W1b, W2b, A2b);

  // ---- gemm_h: h-GEMM (xb input) + router softmax + fused w-GEMM ----
  gemm_h<<<256, 512, 0, stream>>>(xb, W1b, W2b, A2b, wb, rb1, rb2, temp, 1024);

  // ---- out = [x | w] @ [Wb^T ; B2] -> f32, K=1088 (256^2, 8-phase) ----
  gemm_out<<<256, 512, 0, stream>>>(xb, Btb, wb, out, 1024, 1088, 1024, 1088);
}

// Round 22
// 80.582 us; speedup vs baseline: 1.1186x; 1.1186x over previous
//
#include <hip/hip_runtime.h>
#include <hip/hip_bf16.h>
#include <stdint.h>
#include <math.h>

// DynaLoRALinear bf16-MFMA, 3-kernel pipeline (r20 best-known config, reverted).
// prep(weights) -> gemm_h(full-N h-GEMM + x-convert + router softmax + fused
// w=(x@A2^T)*gate; xb written XCD-affine for gemm_out) -> gemm_out(256^2, 8-phase).
// out = [x|w] @ [Wb^T;B2], K=1088.

#define M_TOK 16384

typedef unsigned short u16;
typedef short bf16x8 __attribute__((ext_vector_type(8)));
typedef float f32x4 __attribute__((ext_vector_type(4)));
typedef __attribute__((address_space(3))) uint32_t lds_u32_t;
typedef __attribute__((address_space(1))) const uint32_t glb_u32_t;

__device__ __forceinline__ u16 f2bf(float f) {
  uint32_t u = __builtin_bit_cast(uint32_t, f);
  return (u16)((u + 0x7fffu + ((u >> 16) & 1u)) >> 16);  // RNE
}
__device__ __forceinline__ int cvtpk(float lo, float hi) {  // RNE packed bf16
  int r;
  asm("v_cvt_pk_bf16_f32 %0, %1, %2" : "=v"(r) : "v"(lo), "v"(hi));
  return r;
}

#define VMCNT(n) asm volatile("s_waitcnt vmcnt(%0)" ::"i"(n) : "memory")
#define LGKM0 asm volatile("s_waitcnt lgkmcnt(0)" ::: "memory")
#define BAR asm volatile("s_barrier" ::: "memory")
#define MEMFENCE asm volatile("" ::: "memory")
#define SP(x) __builtin_amdgcn_s_setprio(x)

// ---------------- prep: weight conversions + gathers only (~9 MB) ----------------
__global__ __launch_bounds__(256) void prep_k(const float* __restrict__ Wb,
                                              const float* __restrict__ rW1,
                                              const float* __restrict__ rW2,
                                              const float* __restrict__ loraA,
                                              const float* __restrict__ loraB,
                                              u16* __restrict__ Btb,
                                              u16* __restrict__ W1b,
                                              u16* __restrict__ W2b,
                                              u16* __restrict__ A2b) {
  const int g = blockIdx.x;
  const int tid = threadIdx.x;
  if (g < 1024) {  // Wb -> Btb cols 0..1023 (stride 1088)
    int i = g * 256 + tid;
    int idx = i * 4;
    int row = idx >> 10, col = idx & 1023;
    float4 v = ((const float4*)Wb)[i];
    ushort4 o;
    o.x = f2bf(v.x); o.y = f2bf(v.y); o.z = f2bf(v.z); o.w = f2bf(v.w);
    *(ushort4*)(Btb + (size_t)row * 1088 + col) = o;
  } else if (g < 1536) {  // rW1 -> W1b
    int i = (g - 1024) * 256 + tid;
    float4 v = ((const float4*)rW1)[i];
    ushort4 o;
    o.x = f2bf(v.x); o.y = f2bf(v.y); o.z = f2bf(v.z); o.w = f2bf(v.w);
    ((ushort4*)W1b)[i] = o;
  } else if (g < 1792) {  // lora_B gather -> Btb cols 1024..1087
    int idx = (g - 1536) * 256 + tid;
    int n = idx >> 6, q = idx & 63;
    int e = q >> 3, r = q & 7;
    Btb[(size_t)n * 1088 + 1024 + q] = f2bf(loraB[((size_t)(e * 1024 + n)) * 8 + r]);
  } else if (g < 1856) {  // loraA -> A2b
    int i = (g - 1792) * 256 + tid;
    float4 v = ((const float4*)loraA)[i];
    ushort4 o;
    o.x = f2bf(v.x); o.y = f2bf(v.y); o.z = f2bf(v.z); o.w = f2bf(v.w);
    ((ushort4*)A2b)[i] = o;
  } else {  // W2b [16][512] bf16, rows 8..15 zero
    int i = (g - 1856) * 256 + tid;
    int idx = i * 4;
    int row = idx >> 9, col = idx & 511;
    ushort4 o = {0, 0, 0, 0};
    if (row < 8) {
      float4 v = *(const float4*)(rW2 + (size_t)row * 512 + col);
      o.x = f2bf(v.x); o.y = f2bf(v.y); o.z = f2bf(v.z); o.w = f2bf(v.w);
    }
    ((ushort4*)W2b)[i] = o;
  }
}

// ===== gemm_h: BM=64 x BN=512 (full N), fused x-convert + router + w-GEMM =====
// Per tile: [stage B:8+A2:1][frag reads][issue x:2][VMCNT(11)][cvt+writeA+xb]
// [40 MFMA][LGKM0 VMCNT(3) BAR].  FIFO: enter [x:2,S:1]; +9 +2 = 14;
// VMCNT(11) completes x+S; VMCNT(3) completes B+A2 (9).
// Epilogue: relu-h -> router MFMA logits -> softmax -> g_lds; wb = wacc*gate.
__global__ __launch_bounds__(512, 2) void gemm_h(const float* __restrict__ x,
                                                 const u16* __restrict__ W1b,
                                                 const u16* __restrict__ W2bv,
                                                 const u16* __restrict__ A2bv,
                                                 u16* __restrict__ xb,
                                                 u16* __restrict__ wb,
                                                 const float* __restrict__ b1,
                                                 const float* __restrict__ b2,
                                                 const float* __restrict__ temp,
                                                 const int K) {
  constexpr int ABUF = 64 * 128;            // 8 KB (x tile)
  constexpr int BBUF = 512 * 128;           // 64 KB (W1 tile)
  constexpr int A2BUF = 64 * 128;           // 8 KB (A2 tile)
  constexpr int BUFB = ABUF + BBUF + A2BUF; // 80 KB
  __shared__ __align__(16) uint8_t lds[2 * BUFB];  // 160 KB

  const int tid = threadIdx.x;
  const int lane = tid & 63, w = tid >> 6;
  const int l15 = lane & 15, lhi = lane >> 4;
  const int xorv = (lane & 7) << 4;
  const int c0 = (lhi * 16) ^ xorv;
  const int c1 = (64 + lhi * 16) ^ xorv;

  const int f = blockIdx.x;
  const int m0 = ((f & 7) * 32 + (f >> 3)) * 64;

  const int nk = K >> 6;
  const int rot = (f >> 3) & (nk - 1);
  auto PH = [&](int l) { int lc = l < nk ? l : nk - 1; return (lc + rot) & (nk - 1); };

  const int xrow = tid >> 3, xsub = tid & 7;

  f32x4 acc[4][4] = {};
  f32x4 wacc[4] = {};
  bf16x8 af[4][2], bfv[4][2], a2f[2];
  float4 xA0, xA1, xB0, xB1;

  auto stageBH = [&](int ktp, int b) {
    uint8_t* dst = lds + b * BUFB + ABUF + w * 1024;
#pragma unroll
    for (int i = 0; i < 8; ++i) {
      const int off = i * 8192 + tid * 16;
      const int row = off >> 7;
      const int ss = ((off >> 4) & 7) ^ (row & 7);
      const uint8_t* g =
          (const uint8_t*)W1b + (size_t)row * 2048 + ktp * 128 + ss * 16;
      __builtin_amdgcn_global_load_lds((glb_u32_t*)g, (lds_u32_t*)(dst + i * 8192),
                                       16, 0, 0);
    }
  };
  auto stageA2 = [&](int ktp, int b) {
    uint8_t* dst = lds + b * BUFB + ABUF + BBUF + w * 1024;
    const int off = tid * 16;
    const int row = off >> 7;
    const int ss = ((off >> 4) & 7) ^ (row & 7);
    const uint8_t* g =
        (const uint8_t*)A2bv + (size_t)row * 2048 + ktp * 128 + ss * 16;
    __builtin_amdgcn_global_load_lds((glb_u32_t*)g, (lds_u32_t*)dst, 16, 0, 0);
  };
  auto issueX = [&](int ktp, float4& ra, float4& rb) {
    const float* gp = x + (size_t)(m0 + xrow) * 1024 + ktp * 64 + xsub * 8;
    ra = *(const float4*)gp;
    rb = *(const float4*)(gp + 4);
  };
  auto writeA = [&](int ktp, int b, const float4& ra, const float4& rb) {
    int4 sv;
    sv.x = cvtpk(ra.x, ra.y); sv.y = cvtpk(ra.z, ra.w);
    sv.z = cvtpk(rb.x, rb.y); sv.w = cvtpk(rb.z, rb.w);
    *(int4*)(lds + b * BUFB + xrow * 128 + ((xsub ^ (xrow & 7)) << 4)) = sv;
    *(int4*)(xb + (size_t)(m0 + xrow) * 1024 + ktp * 64 + xsub * 8) = sv;
  };
  auto loadAH = [&](const uint8_t* bufA) {
#pragma unroll
    for (int mf = 0; mf < 4; ++mf) {
      const uint8_t* pr = bufA + (mf * 16 + l15) * 128;
      af[mf][0] = *(const bf16x8*)(pr + c0);
      af[mf][1] = *(const bf16x8*)(pr + c1);
    }
  };
  auto loadBH = [&](const uint8_t* bufB) {
#pragma unroll
    for (int nf = 0; nf < 4; ++nf) {
      const uint8_t* pr = bufB + (w * 64 + nf * 16 + l15) * 128;
      bfv[nf][0] = *(const bf16x8*)(pr + c0);
      bfv[nf][1] = *(const bf16x8*)(pr + c1);
    }
  };
  auto loadA2 = [&](const uint8_t* base) {
    const uint8_t* pr = base + ABUF + BBUF + ((w & 3) * 16 + l15) * 128;
    a2f[0] = *(const bf16x8*)(pr + c0);
    a2f[1] = *(const bf16x8*)(pr + c1);
  };

#define HMM()                                                                  \
  _Pragma("unroll") for (int mf = 0; mf < 4; ++mf)                             \
  _Pragma("unroll") for (int nf = 0; nf < 4; ++nf)                             \
  _Pragma("unroll") for (int ks = 0; ks < 2; ++ks)                             \
      acc[mf][nf] = __builtin_amdgcn_mfma_f32_16x16x32_bf16(                   \
          af[mf][ks], bfv[nf][ks], acc[mf][nf], 0, 0, 0);
#define WMM()                                                                  \
  _Pragma("unroll") for (int mf = 0; mf < 4; ++mf)                             \
  _Pragma("unroll") for (int ks = 0; ks < 2; ++ks)                             \
      wacc[mf] = __builtin_amdgcn_mfma_f32_16x16x32_bf16(                      \
          af[mf][ks], a2f[ks], wacc[mf], 0, 0, 0);

  // ---- prologue: A(rot)->buf0 (convert), B(rot)+A2(rot)->buf0, issue x ----
  {
    const float* gp = x + (size_t)(m0 + xrow) * 1024 + rot * 64 + xsub * 8;
    float4 a = *(const float4*)gp, b = *(const float4*)(gp + 4);
    int4 sv;
    sv.x = cvtpk(a.x, a.y); sv.y = cvtpk(a.z, a.w);
    sv.z = cvtpk(b.x, b.y); sv.w = cvtpk(b.z, b.w);
    *(int4*)(lds + xrow * 128 + ((xsub ^ (xrow & 7)) << 4)) = sv;
    *(int4*)(xb + (size_t)(m0 + xrow) * 1024 + rot * 64 + xsub * 8) = sv;
  }
  stageBH(rot, 0);
  stageA2(rot, 0);
  MEMFENCE;
  issueX(PH(1), xA0, xA1);
  VMCNT(2);  // queue S1+B8+A2'1+x2=12; completes S+B+A2; leaves x(1):2
  LGKM0;
  BAR;

  const int nit = nk >> 1;
#pragma unroll 1
  for (int it = 0; it < nit; ++it) {
    const int t = it * 2;
    // ---- even tile t: p=buf0, q=buf1 ----
    stageBH(PH(t + 1), 1);          // issue B early: fetch flies under ds_reads
    stageA2(PH(t + 1), 1);
    MEMFENCE;
    loadAH(lds);
    loadBH(lds + ABUF);
    loadA2(lds);
    issueX(PH(t + 2), xB0, xB1);
    MEMFENCE;
    VMCNT(11);              // completes x(t+1)+S(t)
    writeA(PH(t + 1), 1, xA0, xA1);
    SP(1); HMM(); WMM(); SP(0);
    LGKM0; VMCNT(3); BAR;   // completes B(t+1)+A2(t+1); leaves x(t+2):2 + S:1
    // ---- odd tile t+1: p=buf1, q=buf0 ----
    stageBH(PH(t + 2), 0);
    stageA2(PH(t + 2), 0);
    MEMFENCE;
    loadAH(lds + BUFB);
    loadBH(lds + BUFB + ABUF);
    loadA2(lds + BUFB);
    issueX(PH(t + 3), xA0, xA1);
    MEMFENCE;
    VMCNT(11);
    writeA(PH(t + 2), 0, xB0, xB1);
    SP(1); HMM(); WMM(); SP(0);
    LGKM0; VMCNT(3); BAR;
  }

  // ---- epilogue ----
  u16* hs = (u16*)lds;                       // [64][520] bf16 = 66560 B
  float* g_lds = (float*)(lds + 66560);      // [64][8] f32 = 2 KB
  __syncthreads();  // drains in-flight clamped prefetches + barrier
#pragma unroll
  for (int mf = 0; mf < 4; ++mf) {
#pragma unroll
    for (int nf = 0; nf < 4; ++nf) {
      const int col = w * 64 + nf * 16 + l15;
#pragma unroll
      for (int j = 0; j < 4; ++j) {
        const int row = mf * 16 + lhi * 4 + j;
        float v = fmaxf(acc[mf][nf][j] + b1[col], 0.f);
        hs[row * 520 + col] = f2bf(v);
      }
    }
  }
  __syncthreads();
  if (w < 4) {  // router: wave w -> logits rows w*16..+15, K=512
    f32x4 acc2 = {};
#pragma unroll
    for (int ks = 0; ks < 16; ++ks) {
      bf16x8 bfrag = *(const bf16x8*)(W2bv + (size_t)l15 * 512 + ks * 32 + lhi * 8);
      bf16x8 afrag = *(const bf16x8*)(hs + (w * 16 + l15) * 520 + ks * 32 + lhi * 8);
      acc2 = __builtin_amdgcn_mfma_f32_16x16x32_bf16(afrag, bfrag, acc2, 0, 0, 0);
    }
    if (l15 < 8) {  // lane holds logit[row=w*16+lhi*4+j][e=l15]
      float t = temp[0];
      float lg[4];
#pragma unroll
      for (int j = 0; j < 4; ++j) lg[j] = (acc2[j] + b2[l15]) / t;
      float mx[4], sm[4];
#pragma unroll
      for (int j = 0; j < 4; ++j) mx[j] = lg[j];
#pragma unroll
      for (int m = 1; m <= 4; m <<= 1)
#pragma unroll
        for (int j = 0; j < 4; ++j) mx[j] = fmaxf(mx[j], __shfl_xor(mx[j], m));
#pragma unroll
      for (int j = 0; j < 4; ++j) { lg[j] = expf(lg[j] - mx[j]); sm[j] = lg[j]; }
#pragma unroll
      for (int m = 1; m <= 4; m <<= 1)
#pragma unroll
        for (int j = 0; j < 4; ++j) sm[j] += __shfl_xor(sm[j], m);
#pragma unroll
      for (int j = 0; j < 4; ++j)
        g_lds[(w * 16 + lhi * 4 + j) * 8 + l15] = lg[j] / sm[j];
    }
  }
  __syncthreads();
  if (w < 4) {  // wb = wacc * gate; wave w owns cols w*16..+15, all 64 rows
#pragma unroll
    for (int mf = 0; mf < 4; ++mf) {
#pragma unroll
      for (int j = 0; j < 4; ++j) {
        const int row = mf * 16 + lhi * 4 + j;
        const int col = w * 16 + l15;
        float v = wacc[mf][j] * g_lds[row * 8 + (col >> 3)];
        wb[(size_t)(m0 + row) * 64 + col] = f2bf(v);
      }
    }
  }
}

// ============ gemm_out: r13-proven 8-phase 256^2 (runtime args, rolled loop) ============
#define MFMA_Q2(mh, nh, AF, BF)                                                \
  _Pragma("unroll") for (int im2 = 0; im2 < 4; ++im2)                          \
  _Pragma("unroll") for (int in2 = 0; in2 < 2; ++in2)                          \
  _Pragma("unroll") for (int ks = 0; ks < 2; ++ks)                             \
      acc[(mh) * 4 + im2][(nh) * 2 + in2] =                                    \
          __builtin_amdgcn_mfma_f32_16x16x32_bf16(                             \
              AF[im2][ks], BF[in2][ks],                                        \
              acc[(mh) * 4 + im2][(nh) * 2 + in2], 0, 0, 0);

__global__ __launch_bounds__(512, 2) void gemm_out(const u16* __restrict__ A,
                                                   const u16* __restrict__ Bt,
                                                   const u16* __restrict__ A2,
                                                   float* __restrict__ C,
                                                   const int N, const int K,
                                                   const int lda, const int ldb) {
  constexpr int BM = 256, BN = 256;
  constexpr int VMC = 4;
  constexpr int BUFB = (BM + BN) * 128;

  __shared__ __align__(16) uint8_t lds[2 * BUFB];

  const int tid = threadIdx.x;
  const int lane = tid & 63, w = tid >> 6;
  const int wr = w >> 2, wcn = w & 3;
  const int l15 = lane & 15, lhi = lane >> 4;
  const int xorv = (lane & 7) << 4;
  const int c0 = (lhi * 16) ^ xorv;
  const int c1 = (64 + lhi * 16) ^ xorv;

  const int f = blockIdx.x;
  const int idx = (f & 7) * 32 + (f >> 3);
  const int gx = N / BN;
  const int m0 = (idx / gx) * BM;
  const int n0 = (idx % gx) * BN;

  const size_t lda_b = (size_t)lda * 2, ldb_b = (size_t)ldb * 2;
  const int nk = K >> 6;
  const int arow0 = (wr * (BM / 2) + l15) * 128;
  const int brow0 = (wcn * (BN / 4) + l15) * 128;

  f32x4 acc[8][4] = {};
  bf16x8 A0f[4][2], A1f[4][2];
  bf16x8 B0f[2][2], B1f[2][2];

  auto stageA = [&](int h, int kt, int b) {
    const int ktc = kt < nk ? kt : nk - 1;
    const bool last = (ktc == nk - 1);
    uint8_t* dst = lds + b * BUFB + h * (BM * 64) + w * 1024;
#pragma unroll
    for (int i = 0; i < 2; ++i) {
      const int off = i * 8192 + tid * 16;
      const int row = h * (BM / 2) + (off >> 7);
      const int ss = ((off >> 4) & 7) ^ (row & 7);
      const uint8_t* g =
          last ? (const uint8_t*)A2 + (size_t)(m0 + row) * 128 + ss * 16
               : (const uint8_t*)A + (size_t)(m0 + row) * lda_b + ktc * 128 + ss * 16;
      __builtin_amdgcn_global_load_lds((glb_u32_t*)g, (lds_u32_t*)(dst + i * 8192),
                                       16, 0, 0);
    }
  };
  auto stageB = [&](int h, int kt, int b) {
    const int ktc = kt < nk ? kt : nk - 1;
    uint8_t* dst = lds + b * BUFB + BM * 128 + h * (BN * 64) + w * 1024;
#pragma unroll
    for (int i = 0; i < 2; ++i) {
      const int off = i * 8192 + tid * 16;
      const int row = h * (BN / 2) + (off >> 7);
      const int ss = ((off >> 4) & 7) ^ (row & 7);
      const uint8_t* g =
          (const uint8_t*)Bt + (size_t)(n0 + row) * ldb_b + ktc * 128 + ss * 16;
      __builtin_amdgcn_global_load_lds((glb_u32_t*)g, (lds_u32_t*)(dst + i * 8192),
                                       16, 0, 0);
    }
  };
  auto loadA = [&](int mh, const uint8_t* buf, bf16x8 (&dst)[4][2]) {
#pragma unroll
    for (int im2 = 0; im2 < 4; ++im2) {
      const uint8_t* p = buf + arow0 + mh * (4 * 2048) + im2 * 2048;
      dst[im2][0] = *(const bf16x8*)(p + c0);
      dst[im2][1] = *(const bf16x8*)(p + c1);
    }
  };
  auto loadB = [&](int nh, const uint8_t* buf, bf16x8 (&dst)[2][2]) {
#pragma unroll
    for (int in2 = 0; in2 < 2; ++in2) {
      const uint8_t* p = buf + BM * 128 + brow0 + nh * (2 * 2048) + in2 * 2048;
      dst[in2][0] = *(const bf16x8*)(p + c0);
      dst[in2][1] = *(const bf16x8*)(p + c1);
    }
  };

  const uint8_t* b0 = lds;
  const uint8_t* b1 = lds + BUFB;

  stageA(0, 0, 0); stageA(1, 0, 0);
  stageB(0, 0, 0); stageB(1, 0, 0);
  stageB(0, 1, 1); stageB(1, 1, 1);
  VMCNT(VMC); BAR;
  loadA(0, b0, A0f); loadB(0, b0, B0f);

  const int NIT = nk >> 1;
#pragma unroll 1
  for (int it = 0; it < NIT; ++it) {
    const int t = it * 2;
    // P1
    stageA(0, t + 1, 1);
    BAR;
    SP(1); MFMA_Q2(0, 0, A0f, B0f); SP(0);
    loadB(1, b0, B1f);
    BAR;
    // P2
    stageA(1, t + 1, 1);
    BAR;
    SP(1); MFMA_Q2(0, 1, A0f, B1f); SP(0);
    loadA(1, b0, A1f);
    BAR;
    // P3
    stageB(0, t + 2, 0);
    BAR;
    SP(1); MFMA_Q2(1, 1, A1f, B1f); SP(0);
    BAR;
    // P4
    stageB(1, t + 2, 0);
    VMCNT(VMC);
    BAR;
    SP(1); MFMA_Q2(1, 0, A1f, B0f); SP(0);
    loadA(0, b1, A0f); loadB(0, b1, B0f);
    BAR;
    // P5
    stageA(0, t + 2, 0);
    BAR;
    SP(1); MFMA_Q2(0, 0, A0f, B0f); SP(0);
    loadB(1, b1, B1f);
    BAR;
    // P6
    stageA(1, t + 2, 0);
    BAR;
    SP(1); MFMA_Q2(0, 1, A0f, B1f); SP(0);
    loadA(1, b1, A1f);
    BAR;
    // P7
    stageB(0, t + 3, 1);
    BAR;
    SP(1); MFMA_Q2(1, 1, A1f, B1f); SP(0);
    BAR;
    // P8
    stageB(1, t + 3, 1);
    VMCNT(VMC);
    BAR;
    SP(1); MFMA_Q2(1, 0, A1f, B0f); SP(0);
    loadA(0, b0, A0f); loadB(0, b0, B0f);
    BAR;
  }

  // tail K-tile (odd nk): buf0 holds tile nk-1; A0f/B0f pre-read at last P8
  if (nk & 1) {
    SP(1); MFMA_Q2(0, 0, A0f, B0f); SP(0);
    loadB(1, b0, B1f);
    SP(1); MFMA_Q2(0, 1, A0f, B1f); SP(0);
    loadA(1, b0, A1f);
    SP(1); MFMA_Q2(1, 1, A1f, B1f); MFMA_Q2(1, 0, A1f, B0f); SP(0);
  }

  // epilogue: plain f32 stores, C/D map col=lane&15, row=(lane>>4)*4+j
#pragma unroll
  for (int im = 0; im < 8; ++im) {
#pragma unroll
    for (int in_ = 0; in_ < 4; ++in_) {
      const int col = n0 + wcn * 64 + in_ * 16 + l15;
#pragma unroll
      for (int j = 0; j < 4; ++j) {
        const int row = m0 + wr * 128 + im * 16 + lhi * 4 + j;
        C[(size_t)row * N + col] = acc[im][in_][j];
      }
    }
  }
}

extern "C" void kernel_launch(void* const* d_in, const int* in_sizes, int n_in,
                              void* d_out, int out_size, void* d_ws, size_t ws_size,
                              hipStream_t stream) {
  const float* x     = (const float*)d_in[0];  // [16384][1024]
  const float* Wb    = (const float*)d_in[1];  // [1024][1024]
  const float* rW1   = (const float*)d_in[2];  // [512][1024]
  const float* rb1   = (const float*)d_in[3];  // [512]
  const float* rW2   = (const float*)d_in[4];  // [8][512]
  const float* rb2   = (const float*)d_in[5];  // [8]
  const float* temp  = (const float*)d_in[6];  // [1]
  const float* loraA = (const float*)d_in[7];  // [64][1024]
  const float* loraB = (const float*)d_in[8];  // [8][1024][8]
  float* out = (float*)d_out;

  uint8_t* p = (uint8_t*)d_ws;
  u16* xb    = (u16*)p;   p += (size_t)M_TOK * 1024 * 2;
  u16* wb    = (u16*)p;   p += (size_t)M_TOK * 64 * 2;
  u16* Btb   = (u16*)p;   p += (size_t)1024 * 1088 * 2;
  u16* W1b   = (u16*)p;   p += (size_t)512 * 1024 * 2;
  u16* W2b   = (u16*)p;   p += (size_t)16 * 512 * 2;
  u16* A2b   = (u16*)p;   p += (size_t)64 * 1024 * 2;

  // ---- prep: weights only (~9 MB) ----
  prep_k<<<1864, 256, 0, stream>>>(Wb, rW1, rW2, loraA, loraB, Btb, W1b, W2b, A2b);

  // ---- gemm_h: h + x->bf16 + router softmax + fused w-GEMM (writes xb, wb) ----
  gemm_h<<<256, 512, 0, stream>>>(x, W1b, W2b, A2b, xb, wb, rb1, rb2, temp, 1024);

  // ---- out = [x | w] @ [Wb^T ; B2] -> f32, K=1088 (256^2, 8-phase) ----
  gemm_out<<<256, 512, 0, stream>>>(xb, Btb, wb, out, 1024, 1088, 1024, 1088);
}